// Round 6
// baseline (282.571 us; speedup 1.0000x reference)
//
#include <hip/hip_runtime.h>
#include <hip/hip_bf16.h>
#include <stdint.h>

#define Bsz   16384
#define Tt    79
#define Dd    256
#define KP    272    // padded K: 256 h + 3 x + 1 bias + 12 zero (granularity 16)
#define LROW  280    // LDS row stride in bf16 elems (560 B)
#define NTILE 32     // batch rows per block; 512 blocks = 2 blocks/CU
#define THR   512    // 8 waves; wave wm owns ONE 32-col m-tile (mt=1) -> small regs, 4 waves/SIMD

typedef __attribute__((ext_vector_type(8)))  short short8;
typedef __attribute__((ext_vector_type(4)))  float float4_;
typedef __attribute__((ext_vector_type(16))) float float16_;

__device__ __forceinline__ unsigned pk2(float a, float b){
  __hip_bfloat162 h = __float22bfloat162_rn(make_float2(a, b));  // v_cvt_pk_bf16_f32
  return *(unsigned*)&h;
}
__device__ __forceinline__ unsigned short f2bf(float f){
  unsigned u = __float_as_uint(f);
  u += 0x7fffu + ((u >> 16) & 1u);
  return (unsigned short)(u >> 16);
}

// Single fused kernel: 512 blocks x 512 threads (2 blocks/CU, target 4 waves/SIMD).
// Each block owns 32 batch rows; h^T (32 x 272 bf16, double-buffered) in LDS.
// Wave wm (0..7) owns m-cols [32*wm, 32*wm+32): A-frags = 17 short8 (68 regs),
// acc = one float16_ (16 regs). U/W_in/b_rnn gathered from global directly
// (coalesced column reads, L2-resident) -- no separate table-build kernel.
__global__ __launch_bounds__(THR, 4) void rnn_all(
    const float* __restrict__ x0,
    const float* __restrict__ x1,
    const float* __restrict__ x2,
    const float* __restrict__ W_in,
    const float* __restrict__ U,
    const float* __restrict__ b_rnn,
    const float* __restrict__ W_d,
    const float* __restrict__ b_d,
    float* __restrict__ out){
  __shared__ __align__(16) short hbuf[2][NTILE * LROW];

  const int tid  = threadIdx.x;
  const int lane = tid & 63;
  const int wm   = tid >> 6;     // 0..7: which 32-col m-tile
  const int nl   = lane & 31;    // n (batch row) for B/C; m-within-tile for A
  const int hi   = lane >> 5;    // k half within a 16-wide k-tile
  const int hi8  = hi * 8;
  const int bbase = blockIdx.x * NTILE;
  const int mcol  = wm * 32 + nl;

  // ---- zero both LDS buffers (h0 = 0, pads = 0) ----
  {
    int4* p = (int4*)&hbuf[0][0];
    const int tot = 2 * NTILE * LROW * 2 / 16;
    int4 z = make_int4(0, 0, 0, 0);
    for (int i = tid; i < tot; i += THR) p[i] = z;
  }
  __syncthreads();

  // bias row k=259 = 1.0 bf16 in both buffers (never overwritten)
  if (tid < NTILE){
    hbuf[0][tid * LROW + 259] = (short)0x3F80;
    hbuf[1][tid * LROW + 259] = (short)0x3F80;
  }

  // stager: 4 lanes per wave, each owns one of the block's 32 batch rows
  const bool stager = (lane < 4);
  const int  sn  = wm * 4 + (lane & 3);
  const int  sgb = bbase + sn;
  if (stager){
    int tr = Tt - 1;
    float a = x0[sgb * Tt + tr];
    float b = x1[sgb * Tt + tr];
    float c = x2[sgb * Tt + tr];
    *(unsigned*)&hbuf[0][sn * LROW + 256] = pk2(a, b);
    hbuf[0][sn * LROW + 258] = (short)f2bf(c);
  }

  // ---- A fragments gathered straight from global U (+ W_in, b_rnn) ----
  // A[m][k]: lane(nl,hi) element j -> k = kt*16 + hi*8 + j, m = mcol.
  short8 afr[17];
  #pragma unroll
  for (int kt = 0; kt < 16; ++kt){
    float f[8];
    #pragma unroll
    for (int j = 0; j < 8; ++j)
      f[j] = U[(kt * 16 + hi8 + j) * 256 + mcol];
    union { unsigned u[4]; short8 s; } r;
    r.u[0] = pk2(f[0], f[1]); r.u[1] = pk2(f[2], f[3]);
    r.u[2] = pk2(f[4], f[5]); r.u[3] = pk2(f[6], f[7]);
    afr[kt] = r.s;
  }
  { // kt = 16: k = 256..271 -> W_in rows 0..2 (k=256..258), b_rnn (k=259), 0 pad
    union { unsigned u[4]; short8 s; } r;
    if (hi == 0){
      r.u[0] = pk2(W_in[0 * 256 + mcol], W_in[1 * 256 + mcol]);
      r.u[1] = pk2(W_in[2 * 256 + mcol], b_rnn[mcol]);
      r.u[2] = 0; r.u[3] = 0;
    } else {
      r.u[0] = 0; r.u[1] = 0; r.u[2] = 0; r.u[3] = 0;
    }
    afr[16] = r.s;
  }

  __syncthreads();

  const float16_ zz16 = {0.f,0.f,0.f,0.f,0.f,0.f,0.f,0.f,
                         0.f,0.f,0.f,0.f,0.f,0.f,0.f,0.f};

  auto step = [&](const short* __restrict__ hb, short* __restrict__ hw, int t){
    // prefetch x(t+1), hidden under the K-loop
    float xa = 0.f, xb = 0.f, xc = 0.f;
    const bool pf = stager && (t < Tt - 1);
    if (pf){
      int tr = Tt - 2 - t;
      xa = x0[sgb * Tt + tr];
      xb = x1[sgb * Tt + tr];
      xc = x2[sgb * Tt + tr];
    }

    float16_ a0;
    const short* bbase_p = &hb[nl * LROW + hi8];   // one base, 17 imm-offset reads
    #pragma unroll
    for (int kt = 0; kt < 17; ++kt){
      short8 b = *(const short8*)(bbase_p + kt * 16);
      a0 = __builtin_amdgcn_mfma_f32_32x32x16_bf16(afr[kt], b,
                                                   kt ? a0 : zz16, 0, 0, 0);
    }

    // relu + pack + write h(t+1); reg group g holds rows m = 8g + 4hi + 0..3
    short* wr = &hw[nl * LROW + wm * 32 + 4 * hi];
    #pragma unroll
    for (int g = 0; g < 4; ++g){
      uint2 w;
      w.x = pk2(fmaxf(a0[4*g+0], 0.f), fmaxf(a0[4*g+1], 0.f));
      w.y = pk2(fmaxf(a0[4*g+2], 0.f), fmaxf(a0[4*g+3], 0.f));
      *(uint2*)(wr + 8 * g) = w;
    }
    if (pf){
      *(unsigned*)&hw[sn * LROW + 256] = pk2(xa, xb);
      hw[sn * LROW + 258] = (short)f2bf(xc);
    }
    __syncthreads();
  };

  // ---- 79 steps: explicit ping-pong (loop-invariant LDS bases) ----
  #pragma unroll 1
  for (int t = 0; t < Tt - 1; t += 2){
    step(&hbuf[0][0], &hbuf[1][0], t);
    step(&hbuf[1][0], &hbuf[0][0], t + 1);
  }
  step(&hbuf[0][0], &hbuf[1][0], Tt - 1);   // t = 78 (even), final h -> buf 1

  // ---- epilogue: out^T = W_d^T h^T + b_d; W_d gathered just-in-time ----
  const short* hb = &hbuf[1][0];
  float16_ o0;
  #pragma unroll
  for (int kt = 0; kt < 17; ++kt){
    union { unsigned u[4]; short8 s; } r;
    if (kt < 16){
      float f[8];
      #pragma unroll
      for (int j = 0; j < 8; ++j)
        f[j] = W_d[(kt * 16 + hi8 + j) * 256 + mcol];
      r.u[0] = pk2(f[0], f[1]); r.u[1] = pk2(f[2], f[3]);
      r.u[2] = pk2(f[4], f[5]); r.u[3] = pk2(f[6], f[7]);
    } else {
      if (hi == 0){ r.u[0] = 0; r.u[1] = pk2(0.f, b_d[mcol]); r.u[2] = 0; r.u[3] = 0; }
      else        { r.u[0] = 0; r.u[1] = 0;                   r.u[2] = 0; r.u[3] = 0; }
    }
    short8 b = *(const short8*)&hb[nl * LROW + kt * 16 + hi8];
    o0 = __builtin_amdgcn_mfma_f32_32x32x16_bf16(r.s, b, kt ? o0 : zz16, 0, 0, 0);
  }
  #pragma unroll
  for (int g = 0; g < 4; ++g){
    float4_ v = {o0[4*g+0], o0[4*g+1], o0[4*g+2], o0[4*g+3]};
    *(float4_*)&out[(bbase + nl) * Dd + wm * 32 + 8 * g + 4 * hi] = v;
  }
}

extern "C" void kernel_launch(void* const* d_in, const int* in_sizes, int n_in,
                              void* d_out, int out_size, void* d_ws, size_t ws_size,
                              hipStream_t stream){
  const float* x0    = (const float*)d_in[0];
  const float* x1    = (const float*)d_in[1];
  const float* x2    = (const float*)d_in[2];
  const float* W_in  = (const float*)d_in[3];
  const float* U     = (const float*)d_in[4];
  const float* b_rnn = (const float*)d_in[5];
  const float* W_d   = (const float*)d_in[6];
  const float* b_d   = (const float*)d_in[7];
  float* out = (float*)d_out;

  rnn_all<<<Bsz / NTILE, THR, 0, stream>>>(x0, x1, x2, W_in, U, b_rnn, W_d, b_d, out);
}